// Round 2
// baseline (22258.038 us; speedup 1.0000x reference)
//
#include <hip/hip_runtime.h>
#include <hip/hip_bf16.h>
#include <math.h>

#define TSEQ 4096
#define EMBD 1024
#define HH   512
#define NTAGS 5
#define NGATE 2048
#define NEGV (-10000.0f)
#define START_TAG 3
#define STOP_TAG 4

typedef unsigned long long u64;
typedef unsigned int u32;

__device__ __forceinline__ float sigm(float x){ return 1.0f/(1.0f+expf(-x)); }

__device__ __forceinline__ u64 pack_pair(float h, u32 tag){
  return ((u64)tag << 32) | (u64)__float_as_uint(h);
}

// ---------------- init: prime h pair buffers (tag 0 = h0, other buffer invalid) ----
__global__ void k_init(const float* __restrict__ h0, u64* __restrict__ hx2){
  int tid = threadIdx.x;
  if (tid < 1024){
    int dir = tid >> 9, u = tid & 511;
    hx2[(dir*2 + 0)*HH + u] = pack_pair(h0[dir*HH + u], 0u);
    hx2[(dir*2 + 1)*HH + u] = pack_pair(0.f, 0xFFFFFFFFu);
  }
}

// ---------------- input projection GEMM (fp32, fused embedding gather + bias) ----
// A[dir][t][n] = sum_k W_ih[n][k] * emb[sent[t]][k] + b[n]
__global__ __launch_bounds__(256) void k_inproj(
    const int* __restrict__ sent, const float* __restrict__ emb,
    const float* __restrict__ Wf, const float* __restrict__ bf,
    const float* __restrict__ Wb, const float* __restrict__ bb,
    float* __restrict__ A){
  __shared__ __align__(16) float As[16][132];
  __shared__ __align__(16) float Bs[16][132];
  __shared__ int srow[128];
  const int tid = threadIdx.x;
  const int t0  = blockIdx.x * 128;
  const int ng0 = blockIdx.y * 128;
  const int dir = (ng0 >= NGATE) ? 1 : 0;
  const float* __restrict__ W    = dir ? Wb : Wf;
  const float* __restrict__ bias = dir ? bb : bf;
  const int n0 = ng0 & (NGATE - 1);
  if (tid < 128) srow[tid] = sent[t0 + tid];
  __syncthreads();
  const int lr = tid >> 2;          // loader row 0..63 (two passes)
  const int kq = (tid & 3) * 4;     // k sub-offset within 16
  const float* ea0 = emb + (size_t)srow[lr]      * EMBD + kq;
  const float* ea1 = emb + (size_t)srow[lr + 64] * EMBD + kq;
  const float* wb0 = W + (size_t)(n0 + lr)      * EMBD + kq;
  const float* wb1 = W + (size_t)(n0 + lr + 64) * EMBD + kq;
  const int tx = tid & 15, ty = tid >> 4;
  float acc[8][8];
  #pragma unroll
  for (int i = 0; i < 8; i++)
    #pragma unroll
    for (int j = 0; j < 8; j++) acc[i][j] = 0.f;

  for (int k0 = 0; k0 < EMBD; k0 += 16){
    float4 va0 = *(const float4*)(ea0 + k0);
    float4 va1 = *(const float4*)(ea1 + k0);
    float4 vb0 = *(const float4*)(wb0 + k0);
    float4 vb1 = *(const float4*)(wb1 + k0);
    As[kq+0][lr] = va0.x; As[kq+1][lr] = va0.y; As[kq+2][lr] = va0.z; As[kq+3][lr] = va0.w;
    As[kq+0][lr+64] = va1.x; As[kq+1][lr+64] = va1.y; As[kq+2][lr+64] = va1.z; As[kq+3][lr+64] = va1.w;
    Bs[kq+0][lr] = vb0.x; Bs[kq+1][lr] = vb0.y; Bs[kq+2][lr] = vb0.z; Bs[kq+3][lr] = vb0.w;
    Bs[kq+0][lr+64] = vb1.x; Bs[kq+1][lr+64] = vb1.y; Bs[kq+2][lr+64] = vb1.z; Bs[kq+3][lr+64] = vb1.w;
    __syncthreads();
    #pragma unroll
    for (int k = 0; k < 16; k++){
      float a[8], b[8];
      *(float4*)&a[0] = *(const float4*)&As[k][ty*8];
      *(float4*)&a[4] = *(const float4*)&As[k][ty*8 + 4];
      #pragma unroll
      for (int j = 0; j < 8; j++) b[j] = Bs[k][tx + 16*j];
      #pragma unroll
      for (int i = 0; i < 8; i++)
        #pragma unroll
        for (int j = 0; j < 8; j++)
          acc[i][j] = fmaf(a[i], b[j], acc[i][j]);
    }
    __syncthreads();
  }
  float bj[8];
  #pragma unroll
  for (int j = 0; j < 8; j++) bj[j] = bias[n0 + tx + 16*j];
  float* Abase = A + (size_t)dir * TSEQ * NGATE;
  #pragma unroll
  for (int i = 0; i < 8; i++){
    float* dst = Abase + (size_t)(t0 + ty*8 + i) * NGATE + n0 + tx;
    #pragma unroll
    for (int j = 0; j < 8; j++) dst[16*j] = acc[i][j] + bj[j];
  }
}

// ---------------- persistent BiLSTM recurrence (1 wave per 2 hidden units) -------
// 512 WGs x 64 threads. WG (dir, wb) owns units {2wb, 2wb+1}. Weights for the 4
// gate rows of each unit live in registers (64 f32/lane). h exchanged through a
// global ping-pong buffer of self-certifying (tag, value) 8-byte atomic pairs:
// tag == step certifies the value; storing tag s+1 certifies all step-s reads of
// this wave completed, so overwriting the tag s-1 slot is WAR-safe.
__global__ __launch_bounds__(64) void k_lstm(
    const float* __restrict__ Whf, const float* __restrict__ Whb,
    const float* __restrict__ c0,
    const float* __restrict__ A, float* __restrict__ hseq,
    u64* __restrict__ hx2){
  const int bid  = blockIdx.x;
  const int dir  = bid >> 8;
  const int wb   = bid & 255;
  const int lane = threadIdx.x;
  const int half = lane >> 5;     // unit select within WG
  const int cc   = lane & 31;     // column chunk
  const int unit = wb*2 + half;   // 0..511
  const float* __restrict__ Wh = dir ? Whb : Whf;

  float wreg[4][16];              // wreg[g][j] = Wh[g*512+unit][j*32+cc]
  #pragma unroll
  for (int g = 0; g < 4; g++){
    const float* wr = Wh + (size_t)(g*HH + unit)*HH + cc;
    #pragma unroll
    for (int j = 0; j < 16; j++) wreg[g][j] = wr[j*32];
  }
  float creg = (cc == 0) ? c0[dir*HH + unit] : 0.f;
  u64* bufs = hx2 + (size_t)dir*2*HH;
  const float* __restrict__ Abase = A + (size_t)dir*TSEQ*NGATE;

  for (int s = 0; s < TSEQ; s++){
    const int t = dir ? (TSEQ - 1 - s) : s;
    // prefetch this step's input-projection values (only reducer lanes need them)
    float a0 = 0.f, a1 = 0.f, a2 = 0.f, a3 = 0.f;
    if (cc == 0){
      const float* ar = Abase + (size_t)t*NGATE + unit;
      a0 = ar[0]; a1 = ar[HH]; a2 = ar[2*HH]; a3 = ar[3*HH];
    }
    // load h_s pairs; poll until each pair's tag == s
    u64* src = bufs + (size_t)(s & 1)*HH;
    u64 v[16];
    #pragma unroll
    for (int j = 0; j < 16; j++)
      v[j] = __hip_atomic_load(&src[j*32 + cc], __ATOMIC_RELAXED, __HIP_MEMORY_SCOPE_AGENT);
    unsigned need = 0xFFFFu;
    while (true){
      #pragma unroll
      for (int j = 0; j < 16; j++)
        if ((need >> j) & 1u)
          if ((u32)(v[j] >> 32) == (u32)s) need &= ~(1u << j);
      if (need == 0u) break;
      #pragma unroll
      for (int j = 0; j < 16; j++)
        if ((need >> j) & 1u)
          v[j] = __hip_atomic_load(&src[j*32 + cc], __ATOMIC_RELAXED, __HIP_MEMORY_SCOPE_AGENT);
    }
    // gate partial sums: 64 FMAs per lane
    float acc0 = 0.f, acc1 = 0.f, acc2 = 0.f, acc3 = 0.f;
    #pragma unroll
    for (int j = 0; j < 16; j++){
      const float hv = __uint_as_float((u32)v[j]);
      acc0 = fmaf(wreg[0][j], hv, acc0);
      acc1 = fmaf(wreg[1][j], hv, acc1);
      acc2 = fmaf(wreg[2][j], hv, acc2);
      acc3 = fmaf(wreg[3][j], hv, acc3);
    }
    // reduce across the 32 column-chunk lanes of each half
    #pragma unroll
    for (int d = 1; d < 32; d <<= 1){
      acc0 += __shfl_xor(acc0, d);
      acc1 += __shfl_xor(acc1, d);
      acc2 += __shfl_xor(acc2, d);
      acc3 += __shfl_xor(acc3, d);
    }
    if (cc == 0){
      const float gi = acc0 + a0, gf = acc1 + a1, gg = acc2 + a2, go = acc3 + a3;
      const float c2 = sigm(gf)*creg + sigm(gi)*tanhf(gg);
      const float h2 = sigm(go)*tanhf(c2);
      creg = c2;
      hseq[((size_t)dir*TSEQ + t)*HH + unit] = h2;
      __hip_atomic_store(&bufs[(size_t)((s + 1) & 1)*HH + unit], pack_pair(h2, (u32)(s + 1)),
                         __ATOMIC_RELAXED, __HIP_MEMORY_SCOPE_AGENT);
    }
  }
}

// ---------------- emission features: feats[t][n] = lstm_out[t] . W_out[n] + b ----
__global__ __launch_bounds__(64) void k_feats(
    const float* __restrict__ Wout, const float* __restrict__ bout,
    const float* __restrict__ hseq, float* __restrict__ feats){
  const int t = blockIdx.x, lane = threadIdx.x;
  const float* hf = hseq + (size_t)t*HH;
  const float* hb = hseq + (size_t)(TSEQ + t)*HH;
  float x[16];
  #pragma unroll
  for (int k = 0; k < 8; k++) x[k]     = hf[lane + 64*k];
  #pragma unroll
  for (int k = 0; k < 8; k++) x[8 + k] = hb[lane + 64*k];
  #pragma unroll
  for (int n = 0; n < NTAGS; n++){
    const float* wr = Wout + (size_t)n*(2*HH);
    float p = 0.f;
    #pragma unroll
    for (int k = 0; k < 8; k++) p = fmaf(x[k],     wr[lane + 64*k],      p);
    #pragma unroll
    for (int k = 0; k < 8; k++) p = fmaf(x[8 + k], wr[HH + lane + 64*k], p);
    #pragma unroll
    for (int d = 1; d < 64; d <<= 1) p += __shfl_xor(p, d);
    if (lane == 0) feats[t*8 + n] = p + bout[n];
  }
}

// ---------------- Viterbi forward + backtrack (1 wave) ----------------
// lane = to*8 + from (5x5 valid). First-max tie-break matches jnp.argmax.
__global__ __launch_bounds__(64) void k_viterbi(
    const float* __restrict__ trans, const float* __restrict__ feats,
    int* __restrict__ bpw, float* __restrict__ out){
  const int lane = threadIdx.x;
  const int to = lane >> 3, from = lane & 7;
  const bool v_to = (to < NTAGS), v_from = (from < NTAGS);
  const float tv = (v_to && v_from) ? trans[to*NTAGS + from] : -1e30f;
  float fv = (from == START_TAG) ? 0.f : NEGV;    // fv for my 'from' tag
  __shared__ float fsh[512];
  for (int t0 = 0; t0 < TSEQ; t0 += 64){
    __syncthreads();
    #pragma unroll
    for (int i = 0; i < 8; i++) fsh[lane + 64*i] = feats[t0*8 + lane + 64*i];
    __syncthreads();
    for (int i = 0; i < 64; i++){
      const int t = t0 + i;
      float bv = fv + tv; int bi = from;
      #pragma unroll
      for (int d = 1; d < 8; d <<= 1){
        float ov = __shfl_xor(bv, d);
        int   oi = __shfl_xor(bi, d);
        if (ov > bv || (ov == bv && oi < bi)){ bv = ov; bi = oi; }
      }
      float nf = bv + fsh[i*8 + to];       // new fv[to] (garbage for to>=5, discarded)
      int wv = 0;
      #pragma unroll
      for (int tt = 0; tt < 5; tt++) wv |= (__shfl(bi, tt*8) & 15) << (4*tt);
      if (lane == 0) bpw[t] = wv;
      float nfv = __shfl(nf, from*8);
      fv = v_from ? nfv : NEGV;
    }
  }
  // terminal: fv + trans[STOP][from]
  float bv = fv + (v_from ? trans[STOP_TAG*NTAGS + from] : -1e30f);
  int bi = from;
  #pragma unroll
  for (int d = 1; d < 8; d <<= 1){
    float ov = __shfl_xor(bv, d);
    int   oi = __shfl_xor(bi, d);
    if (ov > bv || (ov == bv && oi < bi)){ bv = ov; bi = oi; }
  }
  float score = __shfl(bv, 0);
  int btag = __shfl(bi, 0);
  if (lane == 0){ out[0] = score; out[TSEQ] = (float)btag; }   // out[1 + (T-1)]
  int tag = btag;
  for (int b = 63; b >= 0; b--){
    int v = bpw[b*64 + lane];
    for (int i = 63; i >= 0; i--){
      int t = b*64 + i;
      if (t == 0) break;                     // bpw[0] points at virtual START
      int wv2 = __shfl(v, i);
      int prev = (wv2 >> (tag*4)) & 15;
      if (lane == 0) out[t] = (float)prev;   // out[1 + (t-1)]
      tag = prev;
    }
  }
}

extern "C" void kernel_launch(void* const* d_in, const int* in_sizes, int n_in,
                              void* d_out, int out_size, void* d_ws, size_t ws_size,
                              hipStream_t stream) {
  const int*   sent = (const int*)  d_in[0];
  const float* emb  = (const float*)d_in[1];
  const float* Wihf = (const float*)d_in[2];
  const float* Whhf = (const float*)d_in[3];
  const float* bf_  = (const float*)d_in[4];
  const float* Wihb = (const float*)d_in[5];
  const float* Whhb = (const float*)d_in[6];
  const float* bb_  = (const float*)d_in[7];
  const float* Wout = (const float*)d_in[8];
  const float* bout = (const float*)d_in[9];
  const float* trans= (const float*)d_in[10];
  const float* h0   = (const float*)d_in[11];
  const float* c0   = (const float*)d_in[12];
  float* out = (float*)d_out;

  float* ws   = (float*)d_ws;
  float* A    = ws;                                  // [2][T][2048]
  float* hseq = A    + (size_t)2*TSEQ*NGATE;         // [2][T][512]
  u64*   hx2  = (u64*)(hseq + (size_t)2*TSEQ*HH);    // [2][2][512] (tag,val) pairs
  float* fe   = (float*)(hx2 + 2048);                // [T][8]
  int*   bpw  = (int*)(fe + (size_t)TSEQ*8);         // [T] packed nibbles
  (void)ws_size;

  k_init<<<1, 1024, 0, stream>>>(h0, hx2);
  dim3 gg(TSEQ/128, 4096/128);
  k_inproj<<<gg, 256, 0, stream>>>(sent, emb, Wihf, bf_, Wihb, bb_, A);
  k_lstm<<<512, 64, 0, stream>>>(Whhf, Whhb, c0, A, hseq, hx2);
  k_feats<<<TSEQ, 64, 0, stream>>>(Wout, bout, hseq, fe);
  k_viterbi<<<1, 64, 0, stream>>>(trans, fe, bpw, out);
}

// Round 3
// 11283.308 us; speedup vs baseline: 1.9727x; 1.9727x over previous
//
#include <hip/hip_runtime.h>
#include <hip/hip_bf16.h>
#include <math.h>

#define TSEQ 4096
#define EMBD 1024
#define HH   512
#define NTAGS 5
#define NGATE 2048
#define NEGV (-10000.0f)
#define START_TAG 3
#define STOP_TAG 4

typedef unsigned long long u64;
typedef unsigned int u32;

__device__ __forceinline__ float sigm(float x){ return 1.0f/(1.0f+expf(-x)); }

__device__ __forceinline__ u64 pack_pair(float h, u32 tag){
  return ((u64)tag << 32) | (u64)__float_as_uint(h);
}

// ---------------- init: prime h pair buffers (tag 0 = h0, other buffer invalid) ----
__global__ void k_init(const float* __restrict__ h0, u64* __restrict__ hx2){
  int tid = threadIdx.x;
  if (tid < 1024){
    int dir = tid >> 9, u = tid & 511;
    hx2[(dir*2 + 0)*HH + u] = pack_pair(h0[dir*HH + u], 0u);
    hx2[(dir*2 + 1)*HH + u] = pack_pair(0.f, 0xFFFFFFFFu);
  }
}

// ---------------- input projection GEMM (fp32, fused embedding gather + bias) ----
// A[dir][t][n] = sum_k W_ih[n][k] * emb[sent[t]][k] + b[n]
__global__ __launch_bounds__(256) void k_inproj(
    const int* __restrict__ sent, const float* __restrict__ emb,
    const float* __restrict__ Wf, const float* __restrict__ bf,
    const float* __restrict__ Wb, const float* __restrict__ bb,
    float* __restrict__ A){
  __shared__ __align__(16) float As[16][132];
  __shared__ __align__(16) float Bs[16][132];
  __shared__ int srow[128];
  const int tid = threadIdx.x;
  const int t0  = blockIdx.x * 128;
  const int ng0 = blockIdx.y * 128;
  const int dir = (ng0 >= NGATE) ? 1 : 0;
  const float* __restrict__ W    = dir ? Wb : Wf;
  const float* __restrict__ bias = dir ? bb : bf;
  const int n0 = ng0 & (NGATE - 1);
  if (tid < 128) srow[tid] = sent[t0 + tid];
  __syncthreads();
  const int lr = tid >> 2;          // loader row 0..63 (two passes)
  const int kq = (tid & 3) * 4;     // k sub-offset within 16
  const float* ea0 = emb + (size_t)srow[lr]      * EMBD + kq;
  const float* ea1 = emb + (size_t)srow[lr + 64] * EMBD + kq;
  const float* wb0 = W + (size_t)(n0 + lr)      * EMBD + kq;
  const float* wb1 = W + (size_t)(n0 + lr + 64) * EMBD + kq;
  const int tx = tid & 15, ty = tid >> 4;
  float acc[8][8];
  #pragma unroll
  for (int i = 0; i < 8; i++)
    #pragma unroll
    for (int j = 0; j < 8; j++) acc[i][j] = 0.f;

  for (int k0 = 0; k0 < EMBD; k0 += 16){
    float4 va0 = *(const float4*)(ea0 + k0);
    float4 va1 = *(const float4*)(ea1 + k0);
    float4 vb0 = *(const float4*)(wb0 + k0);
    float4 vb1 = *(const float4*)(wb1 + k0);
    As[kq+0][lr] = va0.x; As[kq+1][lr] = va0.y; As[kq+2][lr] = va0.z; As[kq+3][lr] = va0.w;
    As[kq+0][lr+64] = va1.x; As[kq+1][lr+64] = va1.y; As[kq+2][lr+64] = va1.z; As[kq+3][lr+64] = va1.w;
    Bs[kq+0][lr] = vb0.x; Bs[kq+1][lr] = vb0.y; Bs[kq+2][lr] = vb0.z; Bs[kq+3][lr] = vb0.w;
    Bs[kq+0][lr+64] = vb1.x; Bs[kq+1][lr+64] = vb1.y; Bs[kq+2][lr+64] = vb1.z; Bs[kq+3][lr+64] = vb1.w;
    __syncthreads();
    #pragma unroll
    for (int k = 0; k < 16; k++){
      float a[8], b[8];
      *(float4*)&a[0] = *(const float4*)&As[k][ty*8];
      *(float4*)&a[4] = *(const float4*)&As[k][ty*8 + 4];
      #pragma unroll
      for (int j = 0; j < 8; j++) b[j] = Bs[k][tx + 16*j];
      #pragma unroll
      for (int i = 0; i < 8; i++)
        #pragma unroll
        for (int j = 0; j < 8; j++)
          acc[i][j] = fmaf(a[i], b[j], acc[i][j]);
    }
    __syncthreads();
  }
  float bj[8];
  #pragma unroll
  for (int j = 0; j < 8; j++) bj[j] = bias[n0 + tx + 16*j];
  float* Abase = A + (size_t)dir * TSEQ * NGATE;
  #pragma unroll
  for (int i = 0; i < 8; i++){
    float* dst = Abase + (size_t)(t0 + ty*8 + i) * NGATE + n0 + tx;
    #pragma unroll
    for (int j = 0; j < 8; j++) dst[16*j] = acc[i][j] + bj[j];
  }
}

// ---------------- persistent BiLSTM recurrence ----------------
// 64 WGs x 512 thr: 32 WGs/dir, 16 units/WG. Thread map: unit_local = tid>>5,
// gate g = (tid>>3)&3, col-octant q = tid&7 -> each unit's 4 gates x 8 octants
// live in one 32-lane half-wave (matvec reduce + nonlinearity fully in-wave,
// no LDS round trip, no extra barriers).
// h exchange: self-certifying (tag,value) u64 pairs in a global ping-pong
// buffer; ONLY wave 0 of each WG polls (coalesced 4KB rounds), decodes into
// double-buffered LDS; one __syncthreads per step.
__global__ __launch_bounds__(512) void k_lstm(
    const float* __restrict__ Whf, const float* __restrict__ Whb,
    const float* __restrict__ c0,
    const float* __restrict__ A, float* __restrict__ hseq,
    u64* __restrict__ hx2){
  const int bid  = blockIdx.x;
  const int dir  = bid >> 5;
  const int wg   = bid & 31;
  const int tid  = threadIdx.x;
  const int lane = tid & 63;
  const int ul   = tid >> 5;        // unit local 0..15
  const int g    = (tid >> 3) & 3;  // gate i,f,g,o
  const int q    = tid & 7;         // column octant
  const int unit = wg*16 + ul;
  const float* __restrict__ Wh = dir ? Whb : Whf;

  float wreg[64];                   // Wh[g*512+unit][q*64 .. q*64+63]
  {
    const float* wr = Wh + (size_t)(g*HH + unit)*HH + q*64;
    #pragma unroll
    for (int j4 = 0; j4 < 16; j4++){
      float4 vv = *(const float4*)(wr + 4*j4);
      wreg[4*j4+0]=vv.x; wreg[4*j4+1]=vv.y; wreg[4*j4+2]=vv.z; wreg[4*j4+3]=vv.w;
    }
  }
  float creg = 0.f;
  if (g == 0 && q == 0) creg = c0[dir*HH + unit];

  __shared__ __align__(16) float hl[2][8*68];   // [buf][j*68 + c], pad->bank-rotate
  u64* bufs = hx2 + (size_t)dir*2*HH;
  const float* __restrict__ Ab = A + (size_t)dir*TSEQ*NGATE;

  for (int s = 0; s < TSEQ; s++){
    const int t = dir ? (TSEQ - 1 - s) : s;
    // prefetch input-projection value for this thread's gate row (q==0 lanes)
    float av = 0.f;
    if (q == 0) av = Ab[(size_t)t*NGATE + g*HH + unit];

    if (tid < 64){                   // wave 0: poll + stage
      u64* src = bufs + (size_t)(s & 1)*HH;
      u64 v[8];
      #pragma unroll
      for (int j = 0; j < 8; j++)
        v[j] = __hip_atomic_load(&src[j*64 + lane], __ATOMIC_RELAXED, __HIP_MEMORY_SCOPE_AGENT);
      while (true){
        int ok = 1;
        #pragma unroll
        for (int j = 0; j < 8; j++) ok &= ((u32)(v[j] >> 32) == (u32)s);
        if (__all(ok)) break;
        #pragma unroll
        for (int j = 0; j < 8; j++)
          v[j] = __hip_atomic_load(&src[j*64 + lane], __ATOMIC_RELAXED, __HIP_MEMORY_SCOPE_AGENT);
      }
      float* hb = hl[s & 1];
      #pragma unroll
      for (int j = 0; j < 8; j++) hb[j*68 + lane] = __uint_as_float((u32)v[j]);
    }
    __syncthreads();

    // matvec: 64 FMAs from LDS chunk q
    const float* hq = hl[s & 1] + q*68;
    float p0 = 0.f, p1 = 0.f, p2 = 0.f, p3 = 0.f;
    #pragma unroll
    for (int j4 = 0; j4 < 16; j4++){
      float4 h4 = *(const float4*)(hq + 4*j4);
      p0 = fmaf(wreg[4*j4+0], h4.x, p0);
      p1 = fmaf(wreg[4*j4+1], h4.y, p1);
      p2 = fmaf(wreg[4*j4+2], h4.z, p2);
      p3 = fmaf(wreg[4*j4+3], h4.w, p3);
    }
    float acc = ((p0 + p1) + (p2 + p3)) + av;
    acc += __shfl_xor(acc, 1);
    acc += __shfl_xor(acc, 2);
    acc += __shfl_xor(acc, 4);
    // parallel nonlinearity: one transcendental per gate lane
    const float act = (g == 2) ? tanhf(acc) : sigm(acc);
    const float f_ = __shfl_down(act, 8);
    const float g_ = __shfl_down(act, 16);
    const float o_ = __shfl_down(act, 24);
    if (g == 0 && q == 0){
      const float c2 = f_*creg + act*g_;
      const float h2 = o_*tanhf(c2);
      creg = c2;
      hseq[((size_t)dir*TSEQ + t)*HH + unit] = h2;
      __hip_atomic_store(&bufs[(size_t)((s + 1) & 1)*HH + unit],
                         pack_pair(h2, (u32)(s + 1)),
                         __ATOMIC_RELAXED, __HIP_MEMORY_SCOPE_AGENT);
    }
  }
}

// ---------------- emission features: feats[t][n] = lstm_out[t] . W_out[n] + b ----
__global__ __launch_bounds__(64) void k_feats(
    const float* __restrict__ Wout, const float* __restrict__ bout,
    const float* __restrict__ hseq, float* __restrict__ feats){
  const int t = blockIdx.x, lane = threadIdx.x;
  const float* hf = hseq + (size_t)t*HH;
  const float* hb = hseq + (size_t)(TSEQ + t)*HH;
  float x[16];
  #pragma unroll
  for (int k = 0; k < 8; k++) x[k]     = hf[lane + 64*k];
  #pragma unroll
  for (int k = 0; k < 8; k++) x[8 + k] = hb[lane + 64*k];
  #pragma unroll
  for (int n = 0; n < NTAGS; n++){
    const float* wr = Wout + (size_t)n*(2*HH);
    float p = 0.f;
    #pragma unroll
    for (int k = 0; k < 8; k++) p = fmaf(x[k],     wr[lane + 64*k],      p);
    #pragma unroll
    for (int k = 0; k < 8; k++) p = fmaf(x[8 + k], wr[HH + lane + 64*k], p);
    #pragma unroll
    for (int d = 1; d < 64; d <<= 1) p += __shfl_xor(p, d);
    if (lane == 0) feats[t*8 + n] = p + bout[n];
  }
}

// ---------------- Viterbi forward + backtrack (1 wave) ----------------
// lane = to*8 + from (5x5 valid). First-max tie-break matches jnp.argmax.
__global__ __launch_bounds__(64) void k_viterbi(
    const float* __restrict__ trans, const float* __restrict__ feats,
    int* __restrict__ bpw, float* __restrict__ out){
  const int lane = threadIdx.x;
  const int to = lane >> 3, from = lane & 7;
  const bool v_to = (to < NTAGS), v_from = (from < NTAGS);
  const float tv = (v_to && v_from) ? trans[to*NTAGS + from] : -1e30f;
  float fv = (from == START_TAG) ? 0.f : NEGV;    // fv for my 'from' tag
  __shared__ float fsh[512];
  for (int t0 = 0; t0 < TSEQ; t0 += 64){
    __syncthreads();
    #pragma unroll
    for (int i = 0; i < 8; i++) fsh[lane + 64*i] = feats[t0*8 + lane + 64*i];
    __syncthreads();
    for (int i = 0; i < 64; i++){
      const int t = t0 + i;
      float bv = fv + tv; int bi = from;
      #pragma unroll
      for (int d = 1; d < 8; d <<= 1){
        float ov = __shfl_xor(bv, d);
        int   oi = __shfl_xor(bi, d);
        if (ov > bv || (ov == bv && oi < bi)){ bv = ov; bi = oi; }
      }
      float nf = bv + fsh[i*8 + to];       // new fv[to] (garbage for to>=5, discarded)
      int wv = 0;
      #pragma unroll
      for (int tt = 0; tt < 5; tt++) wv |= (__shfl(bi, tt*8) & 15) << (4*tt);
      if (lane == 0) bpw[t] = wv;
      float nfv = __shfl(nf, from*8);
      fv = v_from ? nfv : NEGV;
    }
  }
  // terminal: fv + trans[STOP][from]
  float bv = fv + (v_from ? trans[STOP_TAG*NTAGS + from] : -1e30f);
  int bi = from;
  #pragma unroll
  for (int d = 1; d < 8; d <<= 1){
    float ov = __shfl_xor(bv, d);
    int   oi = __shfl_xor(bi, d);
    if (ov > bv || (ov == bv && oi < bi)){ bv = ov; bi = oi; }
  }
  float score = __shfl(bv, 0);
  int btag = __shfl(bi, 0);
  if (lane == 0){ out[0] = score; out[TSEQ] = (float)btag; }   // out[1 + (T-1)]
  int tag = btag;
  for (int b = 63; b >= 0; b--){
    int v = bpw[b*64 + lane];
    for (int i = 63; i >= 0; i--){
      int t = b*64 + i;
      if (t == 0) break;                     // bpw[0] points at virtual START
      int wv2 = __shfl(v, i);
      int prev = (wv2 >> (tag*4)) & 15;
      if (lane == 0) out[t] = (float)prev;   // out[1 + (t-1)]
      tag = prev;
    }
  }
}

extern "C" void kernel_launch(void* const* d_in, const int* in_sizes, int n_in,
                              void* d_out, int out_size, void* d_ws, size_t ws_size,
                              hipStream_t stream) {
  const int*   sent = (const int*)  d_in[0];
  const float* emb  = (const float*)d_in[1];
  const float* Wihf = (const float*)d_in[2];
  const float* Whhf = (const float*)d_in[3];
  const float* bf_  = (const float*)d_in[4];
  const float* Wihb = (const float*)d_in[5];
  const float* Whhb = (const float*)d_in[6];
  const float* bb_  = (const float*)d_in[7];
  const float* Wout = (const float*)d_in[8];
  const float* bout = (const float*)d_in[9];
  const float* trans= (const float*)d_in[10];
  const float* h0   = (const float*)d_in[11];
  const float* c0   = (const float*)d_in[12];
  float* out = (float*)d_out;

  float* ws   = (float*)d_ws;
  float* A    = ws;                                  // [2][T][2048]
  float* hseq = A    + (size_t)2*TSEQ*NGATE;         // [2][T][512]
  u64*   hx2  = (u64*)(hseq + (size_t)2*TSEQ*HH);    // [2][2][512] (tag,val) pairs
  float* fe   = (float*)(hx2 + 2048);                // [T][8]
  int*   bpw  = (int*)(fe + (size_t)TSEQ*8);         // [T] packed nibbles
  (void)ws_size;

  k_init<<<1, 1024, 0, stream>>>(h0, hx2);
  dim3 gg(TSEQ/128, 4096/128);
  k_inproj<<<gg, 256, 0, stream>>>(sent, emb, Wihf, bf_, Wihb, bb_, A);
  k_lstm<<<64, 512, 0, stream>>>(Whhf, Whhb, c0, A, hseq, hx2);
  k_feats<<<TSEQ, 64, 0, stream>>>(Wout, bout, hseq, fe);
  k_viterbi<<<1, 64, 0, stream>>>(trans, fe, bpw, out);
}